// Round 7
// baseline (148.480 us; speedup 1.0000x reference)
//
#include <hip/hip_runtime.h>
#include <math.h>

// Problem constants (Attention_52355651338291)
#define Bn   4
#define Cc   256    // dim
#define Ll   2048   // sequence length
#define Hh   8      // heads
#define Dd   64     // dim_head
#define HID  512    // Hh*Dd
#define OQKV 1536   // 3*HID

// q-weight scale: (1/sqrt(64)) * log2(e) folded into w_qkv q-rows, so the
// softmax exponential is a bare v_exp_f32 (exp2). Shift 3 -> 3*log2(e),
// folded into the MFMA C-initializer (s starts at -ESHIFT).
#define QSCALE 0.18033688011112042f
#define ESHIFT 4.328085122666891f

typedef _Float16 half4v __attribute__((ext_vector_type(4)));
typedef _Float16 half8v __attribute__((ext_vector_type(8)));
typedef __fp16   fp16x2 __attribute__((ext_vector_type(2)));   // cvt_pkrtz return type
typedef float    f32x16 __attribute__((ext_vector_type(16)));
typedef unsigned uint2v __attribute__((ext_vector_type(2)));

// ---------------------------------------------------------------------------
// Fused: x [b][256 c][2048 l] fp32 -> xT [b][2048 l][256 c] fp16 (64x64 LDS
// transpose) + fp32->fp16 weight conversion (QK scale * log2e folded into
// q-rows).
// ---------------------------------------------------------------------------
__global__ __launch_bounds__(256) void conv_xTw(const float* __restrict__ x,
                                                const float* __restrict__ wqkv,
                                                const float* __restrict__ wout,
                                                _Float16* __restrict__ xT,
                                                _Float16* __restrict__ wqkvh,
                                                _Float16* __restrict__ wouth) {
  __shared__ _Float16 T[64][72];
  const int l0 = blockIdx.x * 64, c0 = blockIdx.y * 64, bz = blockIdx.z;
  const int t = threadIdx.x;
  // ---- weight conversion slice (grid-strided over all 512 blocks) ----
  {
    int gid = (((blockIdx.z * gridDim.y + blockIdx.y) * gridDim.x + blockIdx.x) << 8) + t;
    int nthr = (gridDim.x * gridDim.y * gridDim.z) << 8;   // 131072
    for (int i = gid; i < OQKV * Cc; i += nthr) {
      float v = wqkv[i];
      if (i < HID * Cc) v *= QSCALE;
      wqkvh[i] = (_Float16)v;
    }
    for (int i = gid; i < Cc * HID; i += nthr) wouth[i] = (_Float16)wout[i];
  }
  // ---- x transpose ----
  const float* xb = x + ((size_t)bz * Cc + c0) * Ll + l0;
  {
    int cl = t >> 2;            // channel-local 0..63
    int lq = (t & 3) * 16;      // l-chunk
#pragma unroll
    for (int i = 0; i < 16; i += 4) {
      float4 v = *(const float4*)&xb[(size_t)cl * Ll + lq + i];
      T[lq + i + 0][cl] = (_Float16)v.x;
      T[lq + i + 1][cl] = (_Float16)v.y;
      T[lq + i + 2][cl] = (_Float16)v.z;
      T[lq + i + 3][cl] = (_Float16)v.w;
    }
  }
  __syncthreads();
  {
    int ll = t >> 2;
    int cq = (t & 3) * 16;
    _Float16* dst = xT + ((size_t)bz * Ll + l0 + ll) * Cc + c0 + cq;
    *(half8v*)&dst[0] = *(const half8v*)&T[ll][cq];
    *(half8v*)&dst[8] = *(const half8v*)&T[ll][cq + 8];
  }
}

// ---------------------------------------------------------------------------
// MFMA GEMM: C[bz][m][l] = sum_k A[m][k] * B[bz][l][k]   (B is pre-transposed)
// 128x128 tile, BK=32, 4 waves each owning 64x64 = 2x2 of 32x32x16 mfma.
// MODE 0: fp16 out (qkv proj). MODE 1: fp32 out + bias (out proj).
// ---------------------------------------------------------------------------
template <int MODE>
__global__ __launch_bounds__(256) void gemm_f16(
    const _Float16* __restrict__ A, const _Float16* __restrict__ B,
    const float* __restrict__ bias, void* __restrict__ C, int M, int K) {
  __shared__ _Float16 As[128][40];   // stride 40 halves = 80 B (16B-aligned rows)
  __shared__ _Float16 Bs[128][40];
  const int bz = blockIdx.z;
  const int m0 = blockIdx.y * 128, n0 = blockIdx.x * 128;
  const int t = threadIdx.x;
  const int w = t >> 6, lane = t & 63, lid = lane & 31, lh = lane >> 5;
  const int mw = (w >> 1) * 64, nw = (w & 1) * 64;
  const _Float16* Bb = B + (size_t)bz * Ll * K;

  f32x16 acc[2][2];
#pragma unroll
  for (int a = 0; a < 2; ++a)
#pragma unroll
    for (int b2 = 0; b2 < 2; ++b2)
#pragma unroll
      for (int r = 0; r < 16; ++r) acc[a][b2][r] = 0.0f;

  for (int k0 = 0; k0 < K; k0 += 32) {
    for (int c = t; c < 512; c += 256) {          // 512 16B-chunks per 8KB tile
      int row = c >> 2, kc = (c & 3) * 8;
      *(half8v*)&As[row][kc] = *(const half8v*)&A[(size_t)(m0 + row) * K + k0 + kc];
      *(half8v*)&Bs[row][kc] = *(const half8v*)&Bb[(size_t)(n0 + row) * K + k0 + kc];
    }
    __syncthreads();
#pragma unroll
    for (int kq = 0; kq < 2; ++kq) {
      half8v af[2], bf[2];
#pragma unroll
      for (int ms = 0; ms < 2; ++ms)
        af[ms] = *(const half8v*)&As[mw + ms * 32 + lid][kq * 16 + 8 * lh];
#pragma unroll
      for (int ns = 0; ns < 2; ++ns)
        bf[ns] = *(const half8v*)&Bs[nw + ns * 32 + lid][kq * 16 + 8 * lh];
#pragma unroll
      for (int ms = 0; ms < 2; ++ms)
#pragma unroll
        for (int ns = 0; ns < 2; ++ns)
          acc[ms][ns] = __builtin_amdgcn_mfma_f32_32x32x16_f16(af[ms], bf[ns], acc[ms][ns], 0, 0, 0);
    }
    __syncthreads();
  }
#pragma unroll
  for (int ms = 0; ms < 2; ++ms)
#pragma unroll
    for (int ns = 0; ns < 2; ++ns)
#pragma unroll
      for (int r = 0; r < 16; ++r) {
        int row = m0 + mw + ms * 32 + (r & 3) + 8 * (r >> 2) + 4 * lh;
        int col = n0 + nw + ns * 32 + lid;
        float v = acc[ms][ns][r];
        if (MODE == 1) {
          ((float*)C)[((size_t)bz * M + row) * Ll + col] = v + bias[row];
        } else {
          ((_Float16*)C)[((size_t)bz * M + row) * Ll + col] = (_Float16)v;
        }
      }
}

// ---------------------------------------------------------------------------
// Flash attention v4.1 — VALU diet + XCD K/V locality (compile-type fix:
// cvt_pkrtz returns an __fp16 ext-vector; union member typed accordingly).
//   * XCD-grouping remap (T1): 1-D grid of 512; hw block n -> xcd=n&7,
//     i-tile x=(n>>3)&15, group-slot gs=n>>7, group g=gs*8+xcd=(b,h).
//     All 16 i-tiles sharing one (b,h)'s K/V (0.5MB) land on ONE XCD
//     (4 groups = 2MB <= 4MB L2/XCD). Round-4 FETCH was 69.7MB vs 25.2
//     ideal = cross-XCD K/V re-fetch; this makes K/V L2-resident.
//   * ESHIFT folded into MFMA C-init (s starts at -ESHIFT): -16 v_sub/tile.
//   * P pack via v_cvt_pkrtz_f16_f32 (1 op vs cvt+cvt+pack): -~16 ops/tile.
//   * Everything else (8-wave wg/wj split, permlane32_swap P exchange,
//     wave-specialized double-buffered staging, one barrier/tile) unchanged.
// ---------------------------------------------------------------------------
__device__ inline unsigned pkrtz(float a, float b) {
  union { fp16x2 h; unsigned u; } x;
  x.h = __builtin_amdgcn_cvt_pkrtz(a, b);
  return x.u;
}

__global__ __launch_bounds__(512, 4) void attn_f16(const _Float16* __restrict__ qkv,
                                                   _Float16* __restrict__ aoutT) {
  // ---- XCD-grouping index derivation (bijective over 512 blocks) ----
  const int n = blockIdx.x;
  const int xcd = n & 7;
  const int x = (n >> 3) & 15;     // i-tile
  const int gs = n >> 7;           // 0..3 group slot on this XCD
  const int g = gs * 8 + xcd;      // (b,h) group, 0..31
  const int h = g & 7, b = g >> 3;
  const int i0 = x * 128;

  const int t = threadIdx.x;
  const int w = t >> 6, lane = t & 63, lid = lane & 31, lh = lane >> 5;
  const int wg = w & 3;     // i-strip owner
  const int wj = w >> 2;    // j-half owner
  const _Float16* qb = qkv + ((size_t)b * OQKV + h * Dd) * Ll;   // scale pre-folded
  const _Float16* kb = qb + (size_t)HID * Ll;
  const _Float16* vb = qb + (size_t)(2 * HID) * Ll;

  __shared__ __align__(16) char lds_raw[55296];
  _Float16 (*Qs)[72]     = (_Float16 (*)[72])(lds_raw);              // [128][72]
  _Float16 (*Ks)[64][72] = (_Float16 (*)[64][72])(lds_raw + 18432);  // [2][64][72]
  _Float16 (*Vs)[64][72] = (_Float16 (*)[64][72])(lds_raw + 36864);  // [2][64][72]

  // ---- stage Q transposed + swizzled (once, all 512 threads) ----
  {
    int il = ((t >> 8) << 6) + (t & 15) * 4;   // i row base (step 4)
    int dl = ((t >> 4) & 15) * 4;              // d base
    int cc = dl >> 3, cs = dl & 7;
    half4v rows[4];
#pragma unroll
    for (int r = 0; r < 4; ++r)
      rows[r] = *(const half4v*)&qb[(size_t)(dl + r) * Ll + i0 + il];
#pragma unroll
    for (int c = 0; c < 4; ++c) {
      half4v o;
      o[0] = rows[0][c]; o[1] = rows[1][c]; o[2] = rows[2][c]; o[3] = rows[3][c];
      int row = il + c;
      *(half4v*)&Qs[row][((cc ^ ((row >> 2) & 7)) << 3) | cs] = o;
    }
  }

  // staging role: waves 0-3 stage K, waves 4-7 stage V
  const bool isK = t < 256;
  const int ts = isK ? t : t - 256;
  const int kjl = (ts & 15) * 4, kdl = (ts >> 4) * 4;
  const int kcc = kdl >> 3, kcs = kdl & 7;
  const int vdl = ts >> 2, vjl = (ts & 3) * 16;

  // ---- stage K/V tile 0 ----
  if (isK) {
    half4v rows[4];
#pragma unroll
    for (int r = 0; r < 4; ++r)
      rows[r] = *(const half4v*)&kb[(size_t)(kdl + r) * Ll + kjl];
#pragma unroll
    for (int c = 0; c < 4; ++c) {
      half4v o;
      o[0] = rows[0][c]; o[1] = rows[1][c]; o[2] = rows[2][c]; o[3] = rows[3][c];
      int row = kjl + c;
      *(half4v*)&Ks[0][row][((kcc ^ ((row >> 2) & 7)) << 3) | kcs] = o;
    }
  } else {
    *(half8v*)&Vs[0][vdl][vjl]     = *(const half8v*)&vb[(size_t)vdl * Ll + vjl];
    *(half8v*)&Vs[0][vdl][vjl + 8] = *(const half8v*)&vb[(size_t)vdl * Ll + vjl + 8];
  }
  __syncthreads();

  // Q B-fragments: lane n=i=lid, rows 32*wg+lid (swizzle key (lid>>2)&7)
  const int key = (lid >> 2) & 7;
  half8v qf[4];
#pragma unroll
  for (int kq = 0; kq < 4; ++kq)
    qf[kq] = *(const half8v*)&Qs[32 * wg + lid][((2 * kq + lh) ^ key) << 3];

  float lsum = 0.0f;
  f32x16 oacc[2];
#pragma unroll
  for (int ds = 0; ds < 2; ++ds)
#pragma unroll
    for (int r = 0; r < 16; ++r) oacc[ds][r] = 0.0f;

  const int krow = wj * 32 + lid;

  for (int j0 = 0; j0 < Ll; j0 += 64) {
    const int cur = (j0 >> 6) & 1;
    const int nj = j0 + 64;
    const bool more = nj < Ll;

    // ---- issue next-tile global loads (latency hidden under compute) ----
    half4v krows[4];
    half8v vr0, vr1;
    if (more) {
      if (isK) {
#pragma unroll
        for (int r = 0; r < 4; ++r)
          krows[r] = *(const half4v*)&kb[(size_t)(kdl + r) * Ll + nj + kjl];
      } else {
        vr0 = *(const half8v*)&vb[(size_t)vdl * Ll + nj + vjl];
        vr1 = *(const half8v*)&vb[(size_t)vdl * Ll + nj + vjl + 8];
      }
    }

    // ---- compute this wave's j-half of the tile ----
    f32x16 s;
#pragma unroll
    for (int r = 0; r < 16; ++r) s[r] = -ESHIFT;   // shift folded into C-init
    __builtin_amdgcn_s_setprio(1);
#pragma unroll
    for (int kq = 0; kq < 4; ++kq) {
      half8v kf = *(const half8v*)&Ks[cur][krow][((2 * kq + lh) ^ key) << 3];
      s = __builtin_amdgcn_mfma_f32_32x32x16_f16(kf, qf[kq], s, 0, 0, 0);
    }
    __builtin_amdgcn_s_setprio(0);
    // lane holds S^T[j = wj*32 + (r&3)+8*(r>>2)+4*lh][i = lid]; r = 4q+c
    unsigned W[8];
#pragma unroll
    for (int q = 0; q < 4; ++q) {
      float p0 = __builtin_amdgcn_exp2f(s[4 * q + 0]);
      float p1 = __builtin_amdgcn_exp2f(s[4 * q + 1]);
      float p2 = __builtin_amdgcn_exp2f(s[4 * q + 2]);
      float p3 = __builtin_amdgcn_exp2f(s[4 * q + 3]);
      lsum += (p0 + p1) + (p2 + p3);
      W[2 * q]     = pkrtz(p0, p1);
      W[2 * q + 1] = pkrtz(p2, p3);
    }
    // PV B-frag for k-chunk jq=2wj+f:
    //   u[0] = {own W[4f+0] | partner W[4f+2]},  u[2] = {partner W[4f+0] | own W[4f+2]}
    // v_permlane32_swap(vdst=W0, src=W2): new_vdst = {own W0 | partner W2},
    // new_src = {partner W0 | own W2}  ->  r[0]=u[0], r[1]=u[2].
#pragma unroll
    for (int f = 0; f < 2; ++f) {
      uint2v r02 = __builtin_amdgcn_permlane32_swap(W[4 * f + 0], W[4 * f + 2], false, false);
      uint2v r13 = __builtin_amdgcn_permlane32_swap(W[4 * f + 1], W[4 * f + 3], false, false);
      union { unsigned u[4]; half8v hv; } pu;
      pu.u[0] = r02[0];
      pu.u[1] = r13[0];
      pu.u[2] = r02[1];
      pu.u[3] = r13[1];
      const int jq = 2 * wj + f;
      __builtin_amdgcn_s_setprio(1);
#pragma unroll
      for (int ds = 0; ds < 2; ++ds) {
        half8v vf = *(const half8v*)&Vs[cur][ds * 32 + lid][jq * 16 + 8 * lh];
        oacc[ds] = __builtin_amdgcn_mfma_f32_32x32x16_f16(vf, pu.hv, oacc[ds], 0, 0, 0);
      }
      __builtin_amdgcn_s_setprio(0);
    }

    // ---- write staged tile into the other buffer, then single barrier ----
    if (more) {
      const int nb = cur ^ 1;
      if (isK) {
#pragma unroll
        for (int c = 0; c < 4; ++c) {
          half4v o;
          o[0] = krows[0][c]; o[1] = krows[1][c]; o[2] = krows[2][c]; o[3] = krows[3][c];
          int row = kjl + c;
          *(half4v*)&Ks[nb][row][((kcc ^ ((row >> 2) & 7)) << 3) | kcs] = o;
        }
      } else {
        *(half8v*)&Vs[nb][vdl][vjl]     = vr0;
        *(half8v*)&Vs[nb][vdl][vjl + 8] = vr1;
      }
      __syncthreads();
    }
  }

  // merge lane-halves within wave, then wj pairs via (reused) LDS
  lsum += __shfl_xor(lsum, 32);
  __syncthreads();                      // all LDS tile reads done
  float* red = (float*)lds_raw;         // 4*64*33*4B = 33792 <= 55296
  const int rbase = ((wg << 6) + lane) * 33;   // stride 33 dw: conflict-free
  if (wj == 1) {
#pragma unroll
    for (int ds = 0; ds < 2; ++ds)
#pragma unroll
      for (int r = 0; r < 16; ++r) red[rbase + ds * 16 + r] = oacc[ds][r];
    red[rbase + 32] = lsum;
  }
  __syncthreads();
  if (wj == 0) {
#pragma unroll
    for (int ds = 0; ds < 2; ++ds)
#pragma unroll
      for (int r = 0; r < 16; ++r) oacc[ds][r] += red[rbase + ds * 16 + r];
    lsum += red[rbase + 32];
    float inv = 1.0f / lsum;
    _Float16* dst = aoutT + ((size_t)b * Ll + i0 + 32 * wg + lid) * HID + h * Dd;
#pragma unroll
    for (int ds = 0; ds < 2; ++ds)
#pragma unroll
      for (int g2 = 0; g2 < 4; ++g2) {
        int d = ds * 32 + 8 * g2 + 4 * lh;
        half4v o;
#pragma unroll
        for (int c = 0; c < 4; ++c) o[c] = (_Float16)(oacc[ds][4 * g2 + c] * inv);
        *(half4v*)&dst[d] = o;
      }
  }
}

// ---------------------------------------------------------------------------
// Launch: conv_xTw (transpose + weight cvt) -> qkv GEMM -> attention -> out GEMM
// ws layout (fp16): xT 4.19MB | wqkvh 0.79 | wouth 0.26 | qkvh 25.2 | aoutT 8.4
// ---------------------------------------------------------------------------
extern "C" void kernel_launch(void* const* d_in, const int* in_sizes, int n_in,
                              void* d_out, int out_size, void* d_ws, size_t ws_size,
                              hipStream_t stream) {
  const float* x     = (const float*)d_in[0];  // [4][256][2048]
  const float* w_qkv = (const float*)d_in[1];  // [1536][256]
  const float* w_out = (const float*)d_in[2];  // [256][512]
  const float* b_out = (const float*)d_in[3];  // [256]
  float* out = (float*)d_out;                  // [4][256][2048] fp32

  char* ws = (char*)d_ws;
  _Float16* xT     = (_Float16*)(ws);                       // [4][2048][256]
  _Float16* wqkvh  = (_Float16*)(ws + 4194304);             // [1536][256]
  _Float16* wouth  = (_Float16*)(ws + 4980736);             // [256][512]
  _Float16* qkvh   = (_Float16*)(ws + 5242880);             // [4][1536][2048]
  _Float16* aoutT  = (_Float16*)(ws + 30408704);            // [4][2048][512]

  dim3 blk(256);
  conv_xTw<<<dim3(Ll / 64, Cc / 64, Bn), blk, 0, stream>>>(x, w_qkv, w_out, xT, wqkvh, wouth);
  // qkv = Wqkv_h @ x  (fp16 out, q rows pre-scaled via weights)
  gemm_f16<0><<<dim3(Ll / 128, OQKV / 128, Bn), blk, 0, stream>>>(
      wqkvh, xT, nullptr, qkvh, OQKV, Cc);
  // flash attention (1-D grid, XCD-grouped block remap inside)
  attn_f16<<<dim3(512, 1, 1), dim3(512), 0, stream>>>(qkvh, aoutT);
  // out = Wout_h @ attn + bias (fp32 out)
  gemm_f16<1><<<dim3(Ll / 128, Cc / 128, Bn), blk, 0, stream>>>(
      wouth, aoutT, b_out, out, Cc, HID);
}

// Round 8
// 143.142 us; speedup vs baseline: 1.0373x; 1.0373x over previous
//
#include <hip/hip_runtime.h>
#include <math.h>

// Problem constants (Attention_52355651338291)
#define Bn   4
#define Cc   256    // dim
#define Ll   2048   // sequence length
#define Hh   8      // heads
#define Dd   64     // dim_head
#define HID  512    // Hh*Dd
#define OQKV 1536   // 3*HID

// q-weight scale: (1/sqrt(64)) * log2(e) folded into w_qkv q-rows, so the
// softmax exponential is a bare v_exp_f32 (exp2). Shift 3 -> 3*log2(e),
// folded into the MFMA C-initializer (s starts at -ESHIFT).
#define QSCALE 0.18033688011112042f
#define ESHIFT 4.328085122666891f

typedef _Float16 half4v __attribute__((ext_vector_type(4)));
typedef _Float16 half8v __attribute__((ext_vector_type(8)));
typedef __fp16   fp16x2 __attribute__((ext_vector_type(2)));   // cvt_pkrtz return type
typedef float    f32x16 __attribute__((ext_vector_type(16)));
typedef unsigned uint2v __attribute__((ext_vector_type(2)));

// async global->LDS, 16B per lane; LDS dest is wave-uniform base + lane*16
__device__ __forceinline__ void gload_lds16(const _Float16* g, _Float16* l) {
  __builtin_amdgcn_global_load_lds(
      (const __attribute__((address_space(1))) void*)g,
      (__attribute__((address_space(3))) void*)l, 16, 0, 0);
}

// ---------------------------------------------------------------------------
// Fused: x [b][256 c][2048 l] fp32 -> xT [b][2048 l][256 c] fp16 (64x64 LDS
// transpose) + fp32->fp16 weight conversion (QK scale * log2e folded into
// q-rows).
// ---------------------------------------------------------------------------
__global__ __launch_bounds__(256) void conv_xTw(const float* __restrict__ x,
                                                const float* __restrict__ wqkv,
                                                const float* __restrict__ wout,
                                                _Float16* __restrict__ xT,
                                                _Float16* __restrict__ wqkvh,
                                                _Float16* __restrict__ wouth) {
  __shared__ _Float16 T[64][72];
  const int l0 = blockIdx.x * 64, c0 = blockIdx.y * 64, bz = blockIdx.z;
  const int t = threadIdx.x;
  // ---- weight conversion slice (grid-strided over all 512 blocks) ----
  {
    int gid = (((blockIdx.z * gridDim.y + blockIdx.y) * gridDim.x + blockIdx.x) << 8) + t;
    int nthr = (gridDim.x * gridDim.y * gridDim.z) << 8;   // 131072
    for (int i = gid; i < OQKV * Cc; i += nthr) {
      float v = wqkv[i];
      if (i < HID * Cc) v *= QSCALE;
      wqkvh[i] = (_Float16)v;
    }
    for (int i = gid; i < Cc * HID; i += nthr) wouth[i] = (_Float16)wout[i];
  }
  // ---- x transpose ----
  const float* xb = x + ((size_t)bz * Cc + c0) * Ll + l0;
  {
    int cl = t >> 2;            // channel-local 0..63
    int lq = (t & 3) * 16;      // l-chunk
#pragma unroll
    for (int i = 0; i < 16; i += 4) {
      float4 v = *(const float4*)&xb[(size_t)cl * Ll + lq + i];
      T[lq + i + 0][cl] = (_Float16)v.x;
      T[lq + i + 1][cl] = (_Float16)v.y;
      T[lq + i + 2][cl] = (_Float16)v.z;
      T[lq + i + 3][cl] = (_Float16)v.w;
    }
  }
  __syncthreads();
  {
    int ll = t >> 2;
    int cq = (t & 3) * 16;
    _Float16* dst = xT + ((size_t)bz * Ll + l0 + ll) * Cc + c0 + cq;
    *(half8v*)&dst[0] = *(const half8v*)&T[ll][cq];
    *(half8v*)&dst[8] = *(const half8v*)&T[ll][cq + 8];
  }
}

// ---------------------------------------------------------------------------
// MFMA GEMM v2: C[bz][m][l] = sum_k A[m][k] * B[bz][l][k]  (B pre-transposed)
// 128x128 tile, BK=64, 4 waves each owning 64x64 = 2x2 of 32x32x16 mfma.
//   * Staging via global_load_lds width=16 (no VGPR round-trip; Common
//     mistake #1). LDS linear [128][64]; T2 both-sides swizzle: the per-lane
//     GLOBAL source granule is pre-swizzled g^(row&7) (LDS dest must stay
//     linear), reads XOR the granule with row&7. LDS[row][g]=SRC[row][g^(row&7)].
//   * BK=64 halves barrier count (qkv: 4 iters, out-proj: 8 iters).
//   * Residual 4-way read conflict (32 lanes / 8 granules) is the known T2
//     floor at 128B rows; m151: gll beats conflict-free reg-staging anyway.
// k-accumulation order unchanged -> bit-identical numerics vs v1.
// MODE 0: fp16 out (qkv proj). MODE 1: fp32 out + bias (out proj).
// ---------------------------------------------------------------------------
template <int MODE>
__global__ __launch_bounds__(256) void gemm_f16(
    const _Float16* __restrict__ A, const _Float16* __restrict__ B,
    const float* __restrict__ bias, void* __restrict__ C, int M, int K) {
  __shared__ _Float16 As[128][64];   // linear, 16KB
  __shared__ _Float16 Bs[128][64];
  const int bz = blockIdx.z;
  const int m0 = blockIdx.y * 128, n0 = blockIdx.x * 128;
  const int t = threadIdx.x;
  const int w = t >> 6, lane = t & 63, lid = lane & 31, lh = lane >> 5;
  const int mw = (w >> 1) * 64, nw = (w & 1) * 64;
  const _Float16* Bb = B + (size_t)bz * (size_t)Ll * K;

  // staging geometry: instruction (w,q) covers rows r0=(q*4+w)*8 .. +8;
  // lane i -> row r0+(i>>3), LDS granule i&7, source granule (i&7)^(i>>3).
  const int srow = lane >> 3;                    // row-local 0..7
  const int sgr  = ((lane & 7) ^ srow) << 3;     // pre-swizzled source granule (halves)

  f32x16 acc[2][2];
#pragma unroll
  for (int a = 0; a < 2; ++a)
#pragma unroll
    for (int b2 = 0; b2 < 2; ++b2)
#pragma unroll
      for (int r = 0; r < 16; ++r) acc[a][b2][r] = 0.0f;

  for (int k0 = 0; k0 < K; k0 += 64) {
#pragma unroll
    for (int q = 0; q < 4; ++q) {
      const int r0 = (q * 4 + w) * 8;
      const int row = r0 + srow;
      gload_lds16(&A[(size_t)(m0 + row) * K + k0 + sgr], &As[r0][0]);
      gload_lds16(&Bb[(size_t)(n0 + row) * K + k0 + sgr], &Bs[r0][0]);
    }
    __syncthreads();   // compiler drains vmcnt before barrier
    const int rk = lid & 7;    // row&7 for fragment rows (mw/nw/ms*32 are 0 mod 8)
#pragma unroll
    for (int kq = 0; kq < 4; ++kq) {
      half8v af[2], bf[2];
#pragma unroll
      for (int ms = 0; ms < 2; ++ms)
        af[ms] = *(const half8v*)&As[mw + ms * 32 + lid][((2 * kq + lh) ^ rk) << 3];
#pragma unroll
      for (int ns = 0; ns < 2; ++ns)
        bf[ns] = *(const half8v*)&Bs[nw + ns * 32 + lid][((2 * kq + lh) ^ rk) << 3];
#pragma unroll
      for (int ms = 0; ms < 2; ++ms)
#pragma unroll
        for (int ns = 0; ns < 2; ++ns)
          acc[ms][ns] = __builtin_amdgcn_mfma_f32_32x32x16_f16(af[ms], bf[ns], acc[ms][ns], 0, 0, 0);
    }
    __syncthreads();
  }
#pragma unroll
  for (int ms = 0; ms < 2; ++ms)
#pragma unroll
    for (int ns = 0; ns < 2; ++ns)
#pragma unroll
      for (int r = 0; r < 16; ++r) {
        int row = m0 + mw + ms * 32 + (r & 3) + 8 * (r >> 2) + 4 * lh;
        int col = n0 + nw + ns * 32 + lid;
        float v = acc[ms][ns][r];
        if (MODE == 1) {
          ((float*)C)[((size_t)bz * M + row) * Ll + col] = v + bias[row];
        } else {
          ((_Float16*)C)[((size_t)bz * M + row) * Ll + col] = (_Float16)v;
        }
      }
}

// ---------------------------------------------------------------------------
// Flash attention v4.1 — UNCHANGED from round 7 (52.2 µs, FETCH 12.3MB,
// MfmaUtil 26.6%). Kept byte-identical for clean attribution of the GEMM
// change. See round-7 header comments for design notes.
// ---------------------------------------------------------------------------
__device__ inline unsigned pkrtz(float a, float b) {
  union { fp16x2 h; unsigned u; } x;
  x.h = __builtin_amdgcn_cvt_pkrtz(a, b);
  return x.u;
}

__global__ __launch_bounds__(512, 4) void attn_f16(const _Float16* __restrict__ qkv,
                                                   _Float16* __restrict__ aoutT) {
  // ---- XCD-grouping index derivation (bijective over 512 blocks) ----
  const int n = blockIdx.x;
  const int xcd = n & 7;
  const int x = (n >> 3) & 15;     // i-tile
  const int gs = n >> 7;           // 0..3 group slot on this XCD
  const int g = gs * 8 + xcd;      // (b,h) group, 0..31
  const int h = g & 7, b = g >> 3;
  const int i0 = x * 128;

  const int t = threadIdx.x;
  const int w = t >> 6, lane = t & 63, lid = lane & 31, lh = lane >> 5;
  const int wg = w & 3;     // i-strip owner
  const int wj = w >> 2;    // j-half owner
  const _Float16* qb = qkv + ((size_t)b * OQKV + h * Dd) * Ll;   // scale pre-folded
  const _Float16* kb = qb + (size_t)HID * Ll;
  const _Float16* vb = qb + (size_t)(2 * HID) * Ll;

  __shared__ __align__(16) char lds_raw[55296];
  _Float16 (*Qs)[72]     = (_Float16 (*)[72])(lds_raw);              // [128][72]
  _Float16 (*Ks)[64][72] = (_Float16 (*)[64][72])(lds_raw + 18432);  // [2][64][72]
  _Float16 (*Vs)[64][72] = (_Float16 (*)[64][72])(lds_raw + 36864);  // [2][64][72]

  // ---- stage Q transposed + swizzled (once, all 512 threads) ----
  {
    int il = ((t >> 8) << 6) + (t & 15) * 4;   // i row base (step 4)
    int dl = ((t >> 4) & 15) * 4;              // d base
    int cc = dl >> 3, cs = dl & 7;
    half4v rows[4];
#pragma unroll
    for (int r = 0; r < 4; ++r)
      rows[r] = *(const half4v*)&qb[(size_t)(dl + r) * Ll + i0 + il];
#pragma unroll
    for (int c = 0; c < 4; ++c) {
      half4v o;
      o[0] = rows[0][c]; o[1] = rows[1][c]; o[2] = rows[2][c]; o[3] = rows[3][c];
      int row = il + c;
      *(half4v*)&Qs[row][((cc ^ ((row >> 2) & 7)) << 3) | cs] = o;
    }
  }

  // staging role: waves 0-3 stage K, waves 4-7 stage V
  const bool isK = t < 256;
  const int ts = isK ? t : t - 256;
  const int kjl = (ts & 15) * 4, kdl = (ts >> 4) * 4;
  const int kcc = kdl >> 3, kcs = kdl & 7;
  const int vdl = ts >> 2, vjl = (ts & 3) * 16;

  // ---- stage K/V tile 0 ----
  if (isK) {
    half4v rows[4];
#pragma unroll
    for (int r = 0; r < 4; ++r)
      rows[r] = *(const half4v*)&kb[(size_t)(kdl + r) * Ll + kjl];
#pragma unroll
    for (int c = 0; c < 4; ++c) {
      half4v o;
      o[0] = rows[0][c]; o[1] = rows[1][c]; o[2] = rows[2][c]; o[3] = rows[3][c];
      int row = kjl + c;
      *(half4v*)&Ks[0][row][((kcc ^ ((row >> 2) & 7)) << 3) | kcs] = o;
    }
  } else {
    *(half8v*)&Vs[0][vdl][vjl]     = *(const half8v*)&vb[(size_t)vdl * Ll + vjl];
    *(half8v*)&Vs[0][vdl][vjl + 8] = *(const half8v*)&vb[(size_t)vdl * Ll + vjl + 8];
  }
  __syncthreads();

  // Q B-fragments: lane n=i=lid, rows 32*wg+lid (swizzle key (lid>>2)&7)
  const int key = (lid >> 2) & 7;
  half8v qf[4];
#pragma unroll
  for (int kq = 0; kq < 4; ++kq)
    qf[kq] = *(const half8v*)&Qs[32 * wg + lid][((2 * kq + lh) ^ key) << 3];

  float lsum = 0.0f;
  f32x16 oacc[2];
#pragma unroll
  for (int ds = 0; ds < 2; ++ds)
#pragma unroll
    for (int r = 0; r < 16; ++r) oacc[ds][r] = 0.0f;

  const int krow = wj * 32 + lid;

  for (int j0 = 0; j0 < Ll; j0 += 64) {
    const int cur = (j0 >> 6) & 1;
    const int nj = j0 + 64;
    const bool more = nj < Ll;

    // ---- issue next-tile global loads (latency hidden under compute) ----
    half4v krows[4];
    half8v vr0, vr1;
    if (more) {
      if (isK) {
#pragma unroll
        for (int r = 0; r < 4; ++r)
          krows[r] = *(const half4v*)&kb[(size_t)(kdl + r) * Ll + nj + kjl];
      } else {
        vr0 = *(const half8v*)&vb[(size_t)vdl * Ll + nj + vjl];
        vr1 = *(const half8v*)&vb[(size_t)vdl * Ll + nj + vjl + 8];
      }
    }

    // ---- compute this wave's j-half of the tile ----
    f32x16 s;
#pragma unroll
    for (int r = 0; r < 16; ++r) s[r] = -ESHIFT;   // shift folded into C-init
    __builtin_amdgcn_s_setprio(1);
#pragma unroll
    for (int kq = 0; kq < 4; ++kq) {
      half8v kf = *(const half8v*)&Ks[cur][krow][((2 * kq + lh) ^ key) << 3];
      s = __builtin_amdgcn_mfma_f32_32x32x16_f16(kf, qf[kq], s, 0, 0, 0);
    }
    __builtin_amdgcn_s_setprio(0);
    // lane holds S^T[j = wj*32 + (r&3)+8*(r>>2)+4*lh][i = lid]; r = 4q+c
    unsigned W[8];
#pragma unroll
    for (int q = 0; q < 4; ++q) {
      float p0 = __builtin_amdgcn_exp2f(s[4 * q + 0]);
      float p1 = __builtin_amdgcn_exp2f(s[4 * q + 1]);
      float p2 = __builtin_amdgcn_exp2f(s[4 * q + 2]);
      float p3 = __builtin_amdgcn_exp2f(s[4 * q + 3]);
      lsum += (p0 + p1) + (p2 + p3);
      W[2 * q]     = pkrtz(p0, p1);
      W[2 * q + 1] = pkrtz(p2, p3);
    }
    // PV B-frag for k-chunk jq=2wj+f:
    //   u[0] = {own W[4f+0] | partner W[4f+2]},  u[2] = {partner W[4f+0] | own W[4f+2]}
    // v_permlane32_swap(vdst=W0, src=W2): new_vdst = {own W0 | partner W2},
    // new_src = {partner W0 | own W2}  ->  r[0]=u[0], r[1]=u[2].
#pragma unroll
    for (int f = 0; f < 2; ++f) {
      uint2v r02 = __builtin_amdgcn_permlane32_swap(W[4 * f + 0], W[4 * f + 2], false, false);
      uint2v r13 = __builtin_amdgcn_permlane32_swap(W[4 * f + 1], W[4 * f + 3], false, false);
      union { unsigned u[4]; half8v hv; } pu;
      pu.u[0] = r02[0];
      pu.u[1] = r13[0];
      pu.u[2] = r02[1];
      pu.u[3] = r13[1];
      const int jq = 2 * wj + f;
      __builtin_amdgcn_s_setprio(1);
#pragma unroll
      for (int ds = 0; ds < 2; ++ds) {
        half8v vf = *(const half8v*)&Vs[cur][ds * 32 + lid][jq * 16 + 8 * lh];
        oacc[ds] = __builtin_amdgcn_mfma_f32_32x32x16_f16(vf, pu.hv, oacc[ds], 0, 0, 0);
      }
      __builtin_amdgcn_s_setprio(0);
    }

    // ---- write staged tile into the other buffer, then single barrier ----
    if (more) {
      const int nb = cur ^ 1;
      if (isK) {
#pragma unroll
        for (int c = 0; c < 4; ++c) {
          half4v o;
          o[0] = krows[0][c]; o[1] = krows[1][c]; o[2] = krows[2][c]; o[3] = krows[3][c];
          int row = kjl + c;
          *(half4v*)&Ks[nb][row][((kcc ^ ((row >> 2) & 7)) << 3) | kcs] = o;
        }
      } else {
        *(half8v*)&Vs[nb][vdl][vjl]     = vr0;
        *(half8v*)&Vs[nb][vdl][vjl + 8] = vr1;
      }
      __syncthreads();
    }
  }

  // merge lane-halves within wave, then wj pairs via (reused) LDS
  lsum += __shfl_xor(lsum, 32);
  __syncthreads();                      // all LDS tile reads done
  float* red = (float*)lds_raw;         // 4*64*33*4B = 33792 <= 55296
  const int rbase = ((wg << 6) + lane) * 33;   // stride 33 dw: conflict-free
  if (wj == 1) {
#pragma unroll
    for (int ds = 0; ds < 2; ++ds)
#pragma unroll
      for (int r = 0; r < 16; ++r) red[rbase + ds * 16 + r] = oacc[ds][r];
    red[rbase + 32] = lsum;
  }
  __syncthreads();
  if (wj == 0) {
#pragma unroll
    for (int ds = 0; ds < 2; ++ds)
#pragma unroll
      for (int r = 0; r < 16; ++r) oacc[ds][r] += red[rbase + ds * 16 + r];
    lsum += red[rbase + 32];
    float inv = 1.0f / lsum;
    _Float16* dst = aoutT + ((size_t)b * Ll + i0 + 32 * wg + lid) * HID + h * Dd;
#pragma unroll
    for (int ds = 0; ds < 2; ++ds)
#pragma unroll
      for (int g2 = 0; g2 < 4; ++g2) {
        int d = ds * 32 + 8 * g2 + 4 * lh;
        half4v o;
#pragma unroll
        for (int c = 0; c < 4; ++c) o[c] = (_Float16)(oacc[ds][4 * g2 + c] * inv);
        *(half4v*)&dst[d] = o;
      }
  }
}

// ---------------------------------------------------------------------------
// Launch: conv_xTw (transpose + weight cvt) -> qkv GEMM -> attention -> out GEMM
// ws layout (fp16): xT 4.19MB | wqkvh 0.79 | wouth 0.26 | qkvh 25.2 | aoutT 8.4
// ---------------------------------------------------------------------------
extern "C" void kernel_launch(void* const* d_in, const int* in_sizes, int n_in,
                              void* d_out, int out_size, void* d_ws, size_t ws_size,
                              hipStream_t stream) {
  const float* x     = (const float*)d_in[0];  // [4][256][2048]
  const float* w_qkv = (const float*)d_in[1];  // [1536][256]
  const float* w_out = (const float*)d_in[2];  // [256][512]
  const float* b_out = (const float*)d_in[3];  // [256]
  float* out = (float*)d_out;                  // [4][256][2048] fp32

  char* ws = (char*)d_ws;
  _Float16* xT     = (_Float16*)(ws);                       // [4][2048][256]
  _Float16* wqkvh  = (_Float16*)(ws + 4194304);             // [1536][256]
  _Float16* wouth  = (_Float16*)(ws + 4980736);             // [256][512]
  _Float16* qkvh   = (_Float16*)(ws + 5242880);             // [4][1536][2048]
  _Float16* aoutT  = (_Float16*)(ws + 30408704);            // [4][2048][512]

  dim3 blk(256);
  conv_xTw<<<dim3(Ll / 64, Cc / 64, Bn), blk, 0, stream>>>(x, w_qkv, w_out, xT, wqkvh, wouth);
  // qkv = Wqkv_h @ x  (fp16 out, q rows pre-scaled via weights)
  gemm_f16<0><<<dim3(Ll / 128, OQKV / 128, Bn), blk, 0, stream>>>(
      wqkvh, xT, nullptr, qkvh, OQKV, Cc);
  // flash attention (1-D grid, XCD-grouped block remap inside)
  attn_f16<<<dim3(512, 1, 1), dim3(512), 0, stream>>>(qkvh, aoutT);
  // out = Wout_h @ attn + bias (fp32 out)
  gemm_f16<1><<<dim3(Ll / 128, Cc / 128, Bn), blk, 0, stream>>>(
      wouth, aoutT, b_out, out, Cc, HID);
}